// Round 8
// baseline (214.836 us; speedup 1.0000x reference)
//
#include <hip/hip_runtime.h>
#include <hip/hip_bf16.h>

constexpr int KD = 1024;
constexpr int ND = 512;
constexpr int NT = 32;           // K tiles of 32
constexpr float EPSV = 1e-5f;

using f32x4  = __attribute__((ext_vector_type(4))) float;
using bf16x8 = __attribute__((ext_vector_type(8))) short;
using u16x8  = __attribute__((ext_vector_type(8))) unsigned short;

__device__ __forceinline__ unsigned short f2bf(float f) {
  unsigned int u = __builtin_bit_cast(unsigned int, f);
  return (unsigned short)((u + 0x7fffu + ((u >> 16) & 1u)) >> 16);  // RNE
}

__device__ __forceinline__ u16x8 pack8(float4 a, float4 b) {
  u16x8 v;
  v[0] = f2bf(a.x); v[1] = f2bf(a.y); v[2] = f2bf(a.z); v[3] = f2bf(a.w);
  v[4] = f2bf(b.x); v[5] = f2bf(b.y); v[6] = f2bf(b.z); v[7] = f2bf(b.w);
  return v;
}

__device__ __forceinline__ unsigned short cvt1(float f) {
  __hip_bfloat16 h = __float2bfloat16(f);          // compiler-lowered RNE cvt
  return __builtin_bit_cast(unsigned short, h);
}

#define SCHEDB()  __builtin_amdgcn_sched_barrier(0)

// wconvert: w [512][1024] f32 -> wb in MFMA-fragment-major bf16 layout.
// unit uid = (s*32 + nf)*64 + lane   (16 B each; s = k-slice 0..31, nf = n-frag)
// holds w[n = nf*16 + (lane&15)][k = s*32 + (lane>>4)*8 + e], e = 0..7.
__global__ void wconvert_kernel(const float* __restrict__ w,
                                unsigned short* __restrict__ wb) {
  int uid = blockIdx.x * blockDim.x + threadIdx.x;   // 0..65535
  int s   = uid >> 11;
  int nf  = (uid >> 6) & 31;
  int l   = uid & 63;
  int n   = nf * 16 + (l & 15);
  int k0  = s * 32 + (l >> 4) * 8;
  const float* src = w + n * KD + k0;
  float4 a = *reinterpret_cast<const float4*>(src);
  float4 b = *reinterpret_cast<const float4*>(src + 4);
  *reinterpret_cast<u16x8*>(wb + (size_t)uid * 8) = pack8(a, b);
}

// ===== Fused GEMM(64x512, full N) + bias + LN + scale + softmax =============
// R8: ZERO-BARRIER K-loop via WAVE-PRIVATE A staging.
// 512 thr / 8 waves (1M x 8N), wave tile 64x64, acc[4][4] (64 AGPR).
// Each wave stages the shared 64x32 A-tile into its OWN dbuf LDS region
// (2 x 4 KB; 64 KB/block total -> 2 blocks/CU). ds_write/ds_read are
// same-wave (DS retires in order; compiler inserts lgkmcnt) -> no
// __syncthreads in the K-loop at all. 8x redundant A gloads hit L1.
// R6-vs-R7 A/B showed barrier-domain size is the live lever; this removes
// the domain entirely. B: fragment-major wb from L2, single-buffered.
// Coalescing per A-load instr: 8 rows x 128 B fully-consumed segments
// (same profile as R6 block staging; R5's scatter mistake avoided).
__global__ __launch_bounds__(512, 4)
void fused_kernel(const float* __restrict__ x,
                  const unsigned short* __restrict__ wb,
                  const float* __restrict__ bias,
                  const float* __restrict__ gamma,
                  const float* __restrict__ beta,
                  const float* __restrict__ scalep,
                  float* __restrict__ out) {
  __shared__ unsigned short As[8][2][2048];   // per-wave dbuf, 4 KB each

  const int tid  = threadIdx.x;
  const int lane = tid & 63;
  const int wid  = tid >> 6;        // 0..7 = N eighth: cols wid*64..+63
  const int l15  = lane & 15;
  const int lg   = lane >> 4;       // 0..3

  const long bm  = (long)blockIdx.x * 64;

  f32x4 acc[4][4] = {};

  // ---- wave-private A staging map ----
  // lane covers row = (lane>>3) + q*8 (q=0..3 LO, +32 HI), 16-B chunk lane&7.
  // LDS row = 64 B bf16 = 4 chunks of 16 B; chunk c at c ^ ((row>>1)&3)
  // (row+8k keeps (row>>1)&3 invariant -> one swizzle for all q).
  const int arow = lane >> 3;       // 0..7
  const int akq  = lane & 7;
  const float* asrc = x + (bm + arow) * KD + akq * 4;
  const int awb0 = arow * 64 + (((akq >> 1) ^ ((arow >> 1) & 3)) * 16)
                 + ((akq & 1) * 8);

  // ---- fragment read: lane holds A[mi*16+l15][k=lg*8..+7] ----
  const int ardb = l15 * 64 + (lg ^ ((l15 >> 1) & 3)) * 16;   // + mi*1024

  // ---- B fragment base: frag ni of tile t at ((t*32 + wid*4+ni)*64+lane)*8 us
  const unsigned short* bbase = wb + ((size_t)(wid * 4) * 64 + lane) * 8;

  char* const buf0 = (char*)As[wid][0];
  char* const buf1 = (char*)As[wid][1];

#define ISSUE_A4(t, roff) do { \
    qa0 = *reinterpret_cast<const float4*>(asrc + ((roff) + 0)  * KD + (t) * 32); \
    qa1 = *reinterpret_cast<const float4*>(asrc + ((roff) + 8)  * KD + (t) * 32); \
    qa2 = *reinterpret_cast<const float4*>(asrc + ((roff) + 16) * KD + (t) * 32); \
    qa3 = *reinterpret_cast<const float4*>(asrc + ((roff) + 24) * KD + (t) * 32); } while (0)

#define WRITE_A4(bufp, boff) do { \
    union { unsigned short s[4]; unsigned long long v; } c0_, c1_, c2_, c3_; \
    c0_.s[0] = cvt1(qa0.x); c0_.s[1] = cvt1(qa0.y); \
    c0_.s[2] = cvt1(qa0.z); c0_.s[3] = cvt1(qa0.w); \
    c1_.s[0] = cvt1(qa1.x); c1_.s[1] = cvt1(qa1.y); \
    c1_.s[2] = cvt1(qa1.z); c1_.s[3] = cvt1(qa1.w); \
    c2_.s[0] = cvt1(qa2.x); c2_.s[1] = cvt1(qa2.y); \
    c2_.s[2] = cvt1(qa2.z); c2_.s[3] = cvt1(qa2.w); \
    c3_.s[0] = cvt1(qa3.x); c3_.s[1] = cvt1(qa3.y); \
    c3_.s[2] = cvt1(qa3.z); c3_.s[3] = cvt1(qa3.w); \
    *reinterpret_cast<unsigned long long*>((bufp) + awb0 + (boff) + 0 * 512) = c0_.v; \
    *reinterpret_cast<unsigned long long*>((bufp) + awb0 + (boff) + 1 * 512) = c1_.v; \
    *reinterpret_cast<unsigned long long*>((bufp) + awb0 + (boff) + 2 * 512) = c2_.v; \
    *reinterpret_cast<unsigned long long*>((bufp) + awb0 + (boff) + 3 * 512) = c3_.v; } while (0)

#define ISSUE_B(t) do { \
    const unsigned short* bp_ = bbase + (size_t)(t) * 16384; \
    bc0 = *reinterpret_cast<const bf16x8*>(bp_ + 0 * 512); \
    bc1 = *reinterpret_cast<const bf16x8*>(bp_ + 1 * 512); \
    bc2 = *reinterpret_cast<const bf16x8*>(bp_ + 2 * 512); \
    bc3 = *reinterpret_cast<const bf16x8*>(bp_ + 3 * 512); } while (0)

#define COMPUTE(bufp) do { \
    bf16x8 a0_ = *reinterpret_cast<const bf16x8*>((bufp) + ardb + 0 * 1024); \
    bf16x8 a1_ = *reinterpret_cast<const bf16x8*>((bufp) + ardb + 1 * 1024); \
    bf16x8 a2_ = *reinterpret_cast<const bf16x8*>((bufp) + ardb + 2 * 1024); \
    bf16x8 a3_ = *reinterpret_cast<const bf16x8*>((bufp) + ardb + 3 * 1024); \
    acc[0][0] = __builtin_amdgcn_mfma_f32_16x16x32_bf16(a0_, bc0, acc[0][0], 0, 0, 0); \
    acc[0][1] = __builtin_amdgcn_mfma_f32_16x16x32_bf16(a0_, bc1, acc[0][1], 0, 0, 0); \
    acc[0][2] = __builtin_amdgcn_mfma_f32_16x16x32_bf16(a0_, bc2, acc[0][2], 0, 0, 0); \
    acc[0][3] = __builtin_amdgcn_mfma_f32_16x16x32_bf16(a0_, bc3, acc[0][3], 0, 0, 0); \
    acc[1][0] = __builtin_amdgcn_mfma_f32_16x16x32_bf16(a1_, bc0, acc[1][0], 0, 0, 0); \
    acc[1][1] = __builtin_amdgcn_mfma_f32_16x16x32_bf16(a1_, bc1, acc[1][1], 0, 0, 0); \
    acc[1][2] = __builtin_amdgcn_mfma_f32_16x16x32_bf16(a1_, bc2, acc[1][2], 0, 0, 0); \
    acc[1][3] = __builtin_amdgcn_mfma_f32_16x16x32_bf16(a1_, bc3, acc[1][3], 0, 0, 0); \
    acc[2][0] = __builtin_amdgcn_mfma_f32_16x16x32_bf16(a2_, bc0, acc[2][0], 0, 0, 0); \
    acc[2][1] = __builtin_amdgcn_mfma_f32_16x16x32_bf16(a2_, bc1, acc[2][1], 0, 0, 0); \
    acc[2][2] = __builtin_amdgcn_mfma_f32_16x16x32_bf16(a2_, bc2, acc[2][2], 0, 0, 0); \
    acc[2][3] = __builtin_amdgcn_mfma_f32_16x16x32_bf16(a2_, bc3, acc[2][3], 0, 0, 0); \
    acc[3][0] = __builtin_amdgcn_mfma_f32_16x16x32_bf16(a3_, bc0, acc[3][0], 0, 0, 0); \
    acc[3][1] = __builtin_amdgcn_mfma_f32_16x16x32_bf16(a3_, bc1, acc[3][1], 0, 0, 0); \
    acc[3][2] = __builtin_amdgcn_mfma_f32_16x16x32_bf16(a3_, bc2, acc[3][2], 0, 0, 0); \
    acc[3][3] = __builtin_amdgcn_mfma_f32_16x16x32_bf16(a3_, bc3, acc[3][3], 0, 0, 0); \
    } while (0)

  float4 qa0, qa1, qa2, qa3;
  bf16x8 bc0, bc1, bc2, bc3;

  // ---- prologue: stage A(0) into buf0 (wave-local, no barrier) ----
  ISSUE_A4(0, 0);  WRITE_A4(buf0, 0);
  ISSUE_A4(0, 32); WRITE_A4(buf0, 2048);

  #pragma unroll 2
  for (int t = 0; t < NT; ++t) {
    char* const curp = (t & 1) ? buf1 : buf0;
    char* const nxtp = (t & 1) ? buf0 : buf1;
    const int tp1 = (t + 1 < NT) ? t + 1 : NT - 1;   // clamped tail (harmless)
    ISSUE_B(t);                // oldest in flight: consumed first
    ISSUE_A4(tp1, 0);          // LO half prefetch, covered by COMPUTE
    SCHEDB();
    COMPUTE(curp);             // 4 ds_read + 16 MFMA (waits B via vmcnt)
    WRITE_A4(nxtp, 0);         // LO lands (vmcnt), cvt, ds_write
    ISSUE_A4(tp1, 32);         // HI half: tail latency covered by wave TLP
    WRITE_A4(nxtp, 2048);
  }

  __syncthreads();             // first barrier since launch: LDS -> scratch

  // ========== fused epilogue: bias + LN + scale + softmax (no-max) =========
  // |v| <= sqrt(ND) after LN (var=1) -> exp(v) <= 6.5e9, sum < 3.3e12: f32 ok.
  float* redS = (float*)&As[0][0][0];  // [64][9] partial sums
  float* redQ = redS + 576;            // [64][9] partial sumsq / expsum
  float* rowA = redS + 1152;           // [64] mu
  float* rowB = redS + 1216;           // [64] rstd, later 1/expsum

  const int col0 = wid * 64 + l15;
  const float sc = scalep[0];
  float bs4[4], gs4[4], bb4[4];
  #pragma unroll
  for (int ni = 0; ni < 4; ++ni) {
    bs4[ni] = bias[col0 + ni * 16];
    gs4[ni] = gamma[col0 + ni * 16] * sc;
    bb4[ni] = beta[col0 + ni * 16] * sc;
  }

  // ---- pass 1: bias add + per-row sum / sumsq ----
  #pragma unroll
  for (int mi = 0; mi < 4; ++mi) {
    #pragma unroll
    for (int j = 0; j < 4; ++j) {
      float s = 0.f, q = 0.f;
      #pragma unroll
      for (int ni = 0; ni < 4; ++ni) {
        float v = acc[mi][ni][j] + bs4[ni];
        acc[mi][ni][j] = v;
        s += v;
        q = fmaf(v, v, q);
      }
      #pragma unroll
      for (int m = 1; m < 16; m <<= 1) {
        s += __shfl_xor(s, m, 64);
        q += __shfl_xor(q, m, 64);
      }
      if (l15 == 0) {
        int r = mi * 16 + lg * 4 + j;
        redS[r * 9 + wid] = s;
        redQ[r * 9 + wid] = q;
      }
    }
  }
  __syncthreads();
  if (tid < 64) {
    float s = 0.f, q = 0.f;
    #pragma unroll
    for (int k = 0; k < 8; ++k) { s += redS[tid * 9 + k]; q += redQ[tid * 9 + k]; }
    float mu = s * (1.f / ND);
    rowA[tid] = mu;
    rowB[tid] = rsqrtf(q * (1.f / ND) - mu * mu + EPSV);
  }
  __syncthreads();

  // ---- pass 2: normalize + scale + exp; per-row expsum ----
  #pragma unroll
  for (int mi = 0; mi < 4; ++mi) {
    #pragma unroll
    for (int j = 0; j < 4; ++j) {
      int r = mi * 16 + lg * 4 + j;
      float mu = rowA[r], rs = rowB[r];
      float ps = 0.f;
      #pragma unroll
      for (int ni = 0; ni < 4; ++ni) {
        float v = (acc[mi][ni][j] - mu) * rs;
        v = fmaf(v, gs4[ni], bb4[ni]);
        float e = __expf(v);
        acc[mi][ni][j] = e;
        ps += e;
      }
      #pragma unroll
      for (int m = 1; m < 16; m <<= 1) ps += __shfl_xor(ps, m, 64);
      if (l15 == 0) redQ[r * 9 + wid] = ps;
    }
  }
  __syncthreads();
  if (tid < 64) {
    float s = 0.f;
    #pragma unroll
    for (int k = 0; k < 8; ++k) s += redQ[tid * 9 + k];
    rowB[tid] = 1.f / s;
  }
  __syncthreads();

  // ---- pass 3: store out f32 (non-temporal) ----
  #pragma unroll
  for (int mi = 0; mi < 4; ++mi) {
    #pragma unroll
    for (int j = 0; j < 4; ++j) {
      int r = mi * 16 + lg * 4 + j;
      float rd = rowB[r];
      float* op = out + (bm + r) * ND + col0;
      #pragma unroll
      for (int ni = 0; ni < 4; ++ni)
        __builtin_nontemporal_store(acc[mi][ni][j] * rd, op + ni * 16);
    }
  }
#undef ISSUE_A4
#undef WRITE_A4
#undef ISSUE_B
#undef COMPUTE
}

// trivial last-resort fallback (ws too small; not expected in this harness)
__global__ void fused_fallback(const float* __restrict__ x,
                               const float* __restrict__ wf,
                               const float* __restrict__ bias,
                               const float* __restrict__ gamma,
                               const float* __restrict__ beta,
                               const float* __restrict__ scalep,
                               float* __restrict__ out) {
  long row = blockIdx.x;
  int t = threadIdx.x;
  float s = 0.f;
  const float* xr = x + row * KD;
  const float* wr_ = wf + (size_t)t * KD;
  for (int k = 0; k < KD; ++k) s += xr[k] * wr_[k];
  s += bias[t];
  __shared__ float buf[ND];
  buf[t] = s;
  __syncthreads();
  __shared__ float red[2];
  if (t == 0) {
    float sum = 0.f, sq = 0.f;
    for (int i = 0; i < ND; ++i) { sum += buf[i]; sq += buf[i] * buf[i]; }
    float mu = sum / ND;
    red[0] = mu;
    red[1] = rsqrtf(sq / ND - mu * mu + EPSV);
  }
  __syncthreads();
  float zv = (s - red[0]) * red[1] * gamma[t] * scalep[0] + beta[t] * scalep[0];
  buf[t] = zv;
  __syncthreads();
  __shared__ float red2[2];
  if (t == 0) {
    float mxv = -3.4e38f;
    for (int i = 0; i < ND; ++i) mxv = fmaxf(mxv, buf[i]);
    float den = 0.f;
    for (int i = 0; i < ND; ++i) den += __expf(buf[i] - mxv);
    red2[0] = mxv; red2[1] = 1.f / den;
  }
  __syncthreads();
  out[row * ND + t] = __expf(zv - red2[0]) * red2[1];
}

extern "C" void kernel_launch(void* const* d_in, const int* in_sizes, int n_in,
                              void* d_out, int out_size, void* d_ws, size_t ws_size,
                              hipStream_t stream) {
  const float* x     = (const float*)d_in[0];
  const float* w     = (const float*)d_in[1];
  const float* bias  = (const float*)d_in[2];
  const float* gamma = (const float*)d_in[3];
  const float* beta  = (const float*)d_in[4];
  const float* scale = (const float*)d_in[5];
  float* out = (float*)d_out;

  const int Mrows = in_sizes[0] / KD;                                  // 65536
  const size_t wb_bytes = (size_t)ND * KD * sizeof(unsigned short);    // 1 MB

  if (ws_size >= wb_bytes) {
    unsigned short* wbuf = (unsigned short*)d_ws;
    wconvert_kernel<<<(ND * KD / 8) / 256, 256, 0, stream>>>(w, wbuf);
    fused_kernel<<<Mrows / 64, 512, 0, stream>>>(x, wbuf, bias, gamma, beta,
                                                 scale, out);
  } else {
    fused_fallback<<<Mrows, ND, 0, stream>>>(x, w, bias, gamma, beta, scale, out);
  }
}

// Round 9
// 156.072 us; speedup vs baseline: 1.3765x; 1.3765x over previous
//
#include <hip/hip_runtime.h>
#include <hip/hip_bf16.h>

constexpr int KD = 1024;
constexpr int ND = 512;
constexpr float EPSV = 1e-5f;

using f32x4  = __attribute__((ext_vector_type(4))) float;
using bf16x8 = __attribute__((ext_vector_type(8))) short;
using u16x8  = __attribute__((ext_vector_type(8))) unsigned short;

__device__ __forceinline__ unsigned short f2bf(float f) {
  unsigned int u = __builtin_bit_cast(unsigned int, f);
  return (unsigned short)((u + 0x7fffu + ((u >> 16) & 1u)) >> 16);  // RNE
}

__device__ __forceinline__ u16x8 pack8(float4 a, float4 b) {
  u16x8 v;
  v[0] = f2bf(a.x); v[1] = f2bf(a.y); v[2] = f2bf(a.z); v[3] = f2bf(a.w);
  v[4] = f2bf(b.x); v[5] = f2bf(b.y); v[6] = f2bf(b.z); v[7] = f2bf(b.w);
  return v;
}

#define SCHEDB()  __builtin_amdgcn_sched_barrier(0)

// wconvert: w [512][1024] f32 -> wb in MFMA-fragment-major bf16 layout.
// unit uid = (s*32 + nf)*64 + lane   (16 B each; s = k-slice 0..31, nf = n-frag)
// holds w[n = nf*16 + (lane&15)][k = s*32 + (lane>>4)*8 + e], e = 0..7.
__global__ void wconvert_kernel(const float* __restrict__ w,
                                unsigned short* __restrict__ wb) {
  int uid = blockIdx.x * blockDim.x + threadIdx.x;   // 0..65535
  int s   = uid >> 11;
  int nf  = (uid >> 6) & 31;
  int l   = uid & 63;
  int n   = nf * 16 + (l & 15);
  int k0  = s * 32 + (l >> 4) * 8;
  const float* src = w + n * KD + k0;
  float4 a = *reinterpret_cast<const float4*>(src);
  float4 b = *reinterpret_cast<const float4*>(src + 4);
  *reinterpret_cast<u16x8*>(wb + (size_t)uid * 8) = pack8(a, b);
}

// ===== Fused GEMM(64x512, full N) + bias + LN + scale + softmax =============
// R9: RESIDENT-A. LDS holds a 64x512 (half-K) bf16 A panel (64 KB, 2
// blocks/CU). Staging is block-shared+coalesced and runs TWICE per block
// (not per tile): stage half -> barrier -> 16 barrier-free K-tiles of pure
// {B-gload(L2, reg-dbuf), swizzled ds_read_b128, 16 MFMA} -> barrier ->
// stage half 2 -> barrier -> 16 more tiles. 4 sync points/block vs R6's 16;
// the per-tile gload->cvt->ds_write->barrier chain (R6) and per-wave
// redundancy (R8) are both gone. Swizzle: 16B-quad q at q^(row&7) -> both
// write (8 lanes/quad x 8 quads) and read (uniform q-spread) bank-optimal.
// 512 thr / 8 waves (1M x 8N), wave tile 64x64, acc[4][4] (64 AGPR).
__global__ __launch_bounds__(512, 4)
void fused_kernel(const float* __restrict__ x,
                  const unsigned short* __restrict__ wb,
                  const float* __restrict__ bias,
                  const float* __restrict__ gamma,
                  const float* __restrict__ beta,
                  const float* __restrict__ scalep,
                  float* __restrict__ out) {
  __shared__ unsigned short Ares[64 * 512];    // 64 KB: rows x half-K, swizzled

  const int tid  = threadIdx.x;
  const int lane = tid & 63;
  const int wid  = tid >> 6;        // 0..7 = N eighth: cols wid*64..+63
  const int l15  = lane & 15;
  const int lg   = lane >> 4;       // 0..3
  const int rq   = l15 & 7;         // read-side row&7

  const long bm  = (long)blockIdx.x * 64;

  f32x4 acc[4][4] = {};

  // ---- stage map: thread t -> row r = t>>3, chunk c = t&7 (64 f32 each) ----
  const int r  = tid >> 3;
  const int c  = tid & 7;
  const int rs = r & 7;
  const float* xsrc = x + (bm + r) * KD + c * 64;
  char* const lbase = (char*)Ares + r * 1024 + c * 128;

  // ---- A fragment read base: row l15 (+ mi*16 rows = +16384 B) ----
  const char* const ab = (const char*)Ares + l15 * 1024;

  // ---- B fragment base: frag ni of tile t at ((t*32 + wid*4+ni)*64+lane)*8 us
  const unsigned short* bbase = wb + ((size_t)(wid * 4) * 64 + lane) * 8;

#define STAGE(h) do { \
    const float* sp_ = xsrc + (h) * 512; \
    _Pragma("unroll") \
    for (int b = 0; b < 4; ++b) { \
      float4 f0_ = *reinterpret_cast<const float4*>(sp_ + b * 16 + 0); \
      float4 f1_ = *reinterpret_cast<const float4*>(sp_ + b * 16 + 4); \
      float4 f2_ = *reinterpret_cast<const float4*>(sp_ + b * 16 + 8); \
      float4 f3_ = *reinterpret_cast<const float4*>(sp_ + b * 16 + 12); \
      u16x8 c0_ = pack8(f0_, f1_); \
      u16x8 c1_ = pack8(f2_, f3_); \
      *reinterpret_cast<u16x8*>(lbase + (((2 * b + 0) ^ rs) << 4)) = c0_; \
      *reinterpret_cast<u16x8*>(lbase + (((2 * b + 1) ^ rs) << 4)) = c1_; \
    } } while (0)

#define LOADB(t, r0, r1, r2, r3) do { \
    const unsigned short* bp_ = bbase + (size_t)(t) * 16384; \
    r0 = *reinterpret_cast<const bf16x8*>(bp_ + 0 * 512); \
    r1 = *reinterpret_cast<const bf16x8*>(bp_ + 1 * 512); \
    r2 = *reinterpret_cast<const bf16x8*>(bp_ + 2 * 512); \
    r3 = *reinterpret_cast<const bf16x8*>(bp_ + 3 * 512); } while (0)

#define COMPUTE(ks, B0, B1, B2, B3) do { \
    const int qo_ = ((((ks) * 4 + lg) ^ rq) << 4); \
    bf16x8 a0_ = *reinterpret_cast<const bf16x8*>(ab + 0 * 16384 + qo_); \
    bf16x8 a1_ = *reinterpret_cast<const bf16x8*>(ab + 1 * 16384 + qo_); \
    bf16x8 a2_ = *reinterpret_cast<const bf16x8*>(ab + 2 * 16384 + qo_); \
    bf16x8 a3_ = *reinterpret_cast<const bf16x8*>(ab + 3 * 16384 + qo_); \
    acc[0][0] = __builtin_amdgcn_mfma_f32_16x16x32_bf16(a0_, B0, acc[0][0], 0, 0, 0); \
    acc[0][1] = __builtin_amdgcn_mfma_f32_16x16x32_bf16(a0_, B1, acc[0][1], 0, 0, 0); \
    acc[0][2] = __builtin_amdgcn_mfma_f32_16x16x32_bf16(a0_, B2, acc[0][2], 0, 0, 0); \
    acc[0][3] = __builtin_amdgcn_mfma_f32_16x16x32_bf16(a0_, B3, acc[0][3], 0, 0, 0); \
    acc[1][0] = __builtin_amdgcn_mfma_f32_16x16x32_bf16(a1_, B0, acc[1][0], 0, 0, 0); \
    acc[1][1] = __builtin_amdgcn_mfma_f32_16x16x32_bf16(a1_, B1, acc[1][1], 0, 0, 0); \
    acc[1][2] = __builtin_amdgcn_mfma_f32_16x16x32_bf16(a1_, B2, acc[1][2], 0, 0, 0); \
    acc[1][3] = __builtin_amdgcn_mfma_f32_16x16x32_bf16(a1_, B3, acc[1][3], 0, 0, 0); \
    acc[2][0] = __builtin_amdgcn_mfma_f32_16x16x32_bf16(a2_, B0, acc[2][0], 0, 0, 0); \
    acc[2][1] = __builtin_amdgcn_mfma_f32_16x16x32_bf16(a2_, B1, acc[2][1], 0, 0, 0); \
    acc[2][2] = __builtin_amdgcn_mfma_f32_16x16x32_bf16(a2_, B2, acc[2][2], 0, 0, 0); \
    acc[2][3] = __builtin_amdgcn_mfma_f32_16x16x32_bf16(a2_, B3, acc[2][3], 0, 0, 0); \
    acc[3][0] = __builtin_amdgcn_mfma_f32_16x16x32_bf16(a3_, B0, acc[3][0], 0, 0, 0); \
    acc[3][1] = __builtin_amdgcn_mfma_f32_16x16x32_bf16(a3_, B1, acc[3][1], 0, 0, 0); \
    acc[3][2] = __builtin_amdgcn_mfma_f32_16x16x32_bf16(a3_, B2, acc[3][2], 0, 0, 0); \
    acc[3][3] = __builtin_amdgcn_mfma_f32_16x16x32_bf16(a3_, B3, acc[3][3], 0, 0, 0); \
    } while (0)

  bf16x8 bc0, bc1, bc2, bc3, bn0, bn1, bn2, bn3;

  // ================= half 0: stage, then 16 barrier-free tiles ==============
  STAGE(0);
  __syncthreads();
  LOADB(0, bc0, bc1, bc2, bc3);
  #pragma unroll
  for (int ks = 0; ks < 16; ks += 2) {
    LOADB(ks + 1, bn0, bn1, bn2, bn3);
    SCHEDB();
    COMPUTE(ks, bc0, bc1, bc2, bc3);
    LOADB(ks + 2, bc0, bc1, bc2, bc3);   // at ks=14 this preloads tile 16
    SCHEDB();
    COMPUTE(ks + 1, bn0, bn1, bn2, bn3);
  }

  // ================= half 1 ================================================
  __syncthreads();           // all waves done reading half 0
  STAGE(1);
  __syncthreads();
  #pragma unroll
  for (int ks = 0; ks < 16; ks += 2) {
    LOADB(17 + ks, bn0, bn1, bn2, bn3);
    SCHEDB();
    COMPUTE(ks, bc0, bc1, bc2, bc3);
    LOADB(18 + ks < 32 ? 18 + ks : 31, bc0, bc1, bc2, bc3);  // clamp tail
    SCHEDB();
    COMPUTE(ks + 1, bn0, bn1, bn2, bn3);
  }
  __syncthreads();           // drain LDS reads before scratch overlay

  // ========== fused epilogue: bias + LN + scale + softmax (no-max) =========
  // |v| <= sqrt(ND) after LN (var=1) -> exp(v) <= 6.5e9, sum < 3.3e12: f32 ok.
  float* redS = (float*)Ares;   // [64][9] partial sums
  float* redQ = redS + 576;     // [64][9] partial sumsq / expsum
  float* rowA = redS + 1152;    // [64] mu
  float* rowB = redS + 1216;    // [64] rstd, later 1/expsum

  const int col0 = wid * 64 + l15;
  const float sc = scalep[0];
  float bs4[4], gs4[4], bb4[4];
  #pragma unroll
  for (int ni = 0; ni < 4; ++ni) {
    bs4[ni] = bias[col0 + ni * 16];
    gs4[ni] = gamma[col0 + ni * 16] * sc;
    bb4[ni] = beta[col0 + ni * 16] * sc;
  }

  // ---- pass 1: bias add + per-row sum / sumsq ----
  #pragma unroll
  for (int mi = 0; mi < 4; ++mi) {
    #pragma unroll
    for (int j = 0; j < 4; ++j) {
      float s = 0.f, q = 0.f;
      #pragma unroll
      for (int ni = 0; ni < 4; ++ni) {
        float v = acc[mi][ni][j] + bs4[ni];
        acc[mi][ni][j] = v;
        s += v;
        q = fmaf(v, v, q);
      }
      #pragma unroll
      for (int m = 1; m < 16; m <<= 1) {
        s += __shfl_xor(s, m, 64);
        q += __shfl_xor(q, m, 64);
      }
      if (l15 == 0) {
        int rr = mi * 16 + lg * 4 + j;
        redS[rr * 9 + wid] = s;
        redQ[rr * 9 + wid] = q;
      }
    }
  }
  __syncthreads();
  if (tid < 64) {
    float s = 0.f, q = 0.f;
    #pragma unroll
    for (int k = 0; k < 8; ++k) { s += redS[tid * 9 + k]; q += redQ[tid * 9 + k]; }
    float mu = s * (1.f / ND);
    rowA[tid] = mu;
    rowB[tid] = rsqrtf(q * (1.f / ND) - mu * mu + EPSV);
  }
  __syncthreads();

  // ---- pass 2: normalize + scale + exp; per-row expsum ----
  #pragma unroll
  for (int mi = 0; mi < 4; ++mi) {
    #pragma unroll
    for (int j = 0; j < 4; ++j) {
      int rr = mi * 16 + lg * 4 + j;
      float mu = rowA[rr], rstd = rowB[rr];
      float ps = 0.f;
      #pragma unroll
      for (int ni = 0; ni < 4; ++ni) {
        float v = (acc[mi][ni][j] - mu) * rstd;
        v = fmaf(v, gs4[ni], bb4[ni]);
        float e = __expf(v);
        acc[mi][ni][j] = e;
        ps += e;
      }
      #pragma unroll
      for (int m = 1; m < 16; m <<= 1) ps += __shfl_xor(ps, m, 64);
      if (l15 == 0) redQ[rr * 9 + wid] = ps;
    }
  }
  __syncthreads();
  if (tid < 64) {
    float s = 0.f;
    #pragma unroll
    for (int k = 0; k < 8; ++k) s += redQ[tid * 9 + k];
    rowB[tid] = 1.f / s;
  }
  __syncthreads();

  // ---- pass 3: store out f32 (non-temporal) ----
  #pragma unroll
  for (int mi = 0; mi < 4; ++mi) {
    #pragma unroll
    for (int j = 0; j < 4; ++j) {
      int rr = mi * 16 + lg * 4 + j;
      float rd = rowB[rr];
      float* op = out + (bm + rr) * ND + col0;
      #pragma unroll
      for (int ni = 0; ni < 4; ++ni)
        __builtin_nontemporal_store(acc[mi][ni][j] * rd, op + ni * 16);
    }
  }
#undef STAGE
#undef LOADB
#undef COMPUTE
}

// trivial last-resort fallback (ws too small; not expected in this harness)
__global__ void fused_fallback(const float* __restrict__ x,
                               const float* __restrict__ wf,
                               const float* __restrict__ bias,
                               const float* __restrict__ gamma,
                               const float* __restrict__ beta,
                               const float* __restrict__ scalep,
                               float* __restrict__ out) {
  long row = blockIdx.x;
  int t = threadIdx.x;
  float s = 0.f;
  const float* xr = x + row * KD;
  const float* wr_ = wf + (size_t)t * KD;
  for (int k = 0; k < KD; ++k) s += xr[k] * wr_[k];
  s += bias[t];
  __shared__ float buf[ND];
  buf[t] = s;
  __syncthreads();
  __shared__ float red[2];
  if (t == 0) {
    float sum = 0.f, sq = 0.f;
    for (int i = 0; i < ND; ++i) { sum += buf[i]; sq += buf[i] * buf[i]; }
    float mu = sum / ND;
    red[0] = mu;
    red[1] = rsqrtf(sq / ND - mu * mu + EPSV);
  }
  __syncthreads();
  float zv = (s - red[0]) * red[1] * gamma[t] * scalep[0] + beta[t] * scalep[0];
  buf[t] = zv;
  __syncthreads();
  __shared__ float red2[2];
  if (t == 0) {
    float mxv = -3.4e38f;
    for (int i = 0; i < ND; ++i) mxv = fmaxf(mxv, buf[i]);
    float den = 0.f;
    for (int i = 0; i < ND; ++i) den += __expf(buf[i] - mxv);
    red2[0] = mxv; red2[1] = 1.f / den;
  }
  __syncthreads();
  out[row * ND + t] = __expf(zv - red2[0]) * red2[1];
}

extern "C" void kernel_launch(void* const* d_in, const int* in_sizes, int n_in,
                              void* d_out, int out_size, void* d_ws, size_t ws_size,
                              hipStream_t stream) {
  const float* x     = (const float*)d_in[0];
  const float* w     = (const float*)d_in[1];
  const float* bias  = (const float*)d_in[2];
  const float* gamma = (const float*)d_in[3];
  const float* beta  = (const float*)d_in[4];
  const float* scale = (const float*)d_in[5];
  float* out = (float*)d_out;

  const int Mrows = in_sizes[0] / KD;                                  // 65536
  const size_t wb_bytes = (size_t)ND * KD * sizeof(unsigned short);    // 1 MB

  if (ws_size >= wb_bytes) {
    unsigned short* wbuf = (unsigned short*)d_ws;
    wconvert_kernel<<<(ND * KD / 8) / 256, 256, 0, stream>>>(w, wbuf);
    fused_kernel<<<Mrows / 64, 512, 0, stream>>>(x, wbuf, bias, gamma, beta,
                                                 scale, out);
  } else {
    fused_fallback<<<Mrows, ND, 0, stream>>>(x, w, bias, gamma, beta, scale, out);
  }
}

// Round 10
// 119.068 us; speedup vs baseline: 1.8043x; 1.3108x over previous
//
#include <hip/hip_runtime.h>
#include <hip/hip_bf16.h>

constexpr int KD = 1024;
constexpr int ND = 512;
constexpr int NT = 32;           // K tiles of 32
constexpr float EPSV = 1e-5f;

using f32x4  = __attribute__((ext_vector_type(4))) float;
using bf16x8 = __attribute__((ext_vector_type(8))) short;
using u16x8  = __attribute__((ext_vector_type(8))) unsigned short;

__device__ __forceinline__ unsigned short f2bf(float f) {
  unsigned int u = __builtin_bit_cast(unsigned int, f);
  return (unsigned short)((u + 0x7fffu + ((u >> 16) & 1u)) >> 16);  // RNE
}

__device__ __forceinline__ u16x8 pack8(float4 a, float4 b) {
  u16x8 v;
  v[0] = f2bf(a.x); v[1] = f2bf(a.y); v[2] = f2bf(a.z); v[3] = f2bf(a.w);
  v[4] = f2bf(b.x); v[5] = f2bf(b.y); v[6] = f2bf(b.z); v[7] = f2bf(b.w);
  return v;
}

__device__ __forceinline__ unsigned short cvt1(float f) {
  __hip_bfloat16 h = __float2bfloat16(f);          // compiler-lowered RNE cvt
  return __builtin_bit_cast(unsigned short, h);
}

#define SCHEDB()  __builtin_amdgcn_sched_barrier(0)

// wconvert: w [512][1024] f32 -> wb in MFMA-fragment-major bf16 layout.
// unit uid = (s*32 + nf)*64 + lane   (16 B each; s = k-slice 0..31, nf = n-frag)
// holds w[n = nf*16 + (lane&15)][k = s*32 + (lane>>4)*8 + e], e = 0..7.
__global__ void wconvert_kernel(const float* __restrict__ w,
                                unsigned short* __restrict__ wb) {
  int uid = blockIdx.x * blockDim.x + threadIdx.x;   // 0..65535
  int s   = uid >> 11;
  int nf  = (uid >> 6) & 31;
  int l   = uid & 63;
  int n   = nf * 16 + (l & 15);
  int k0  = s * 32 + (l >> 4) * 8;
  const float* src = w + n * KD + k0;
  float4 a = *reinterpret_cast<const float4*>(src);
  float4 b = *reinterpret_cast<const float4*>(src + 4);
  *reinterpret_cast<u16x8*>(wb + (size_t)uid * 8) = pack8(a, b);
}

// ===== Fused GEMM(64x512, full N) + bias + LN + scale + softmax =============
// R10 = R6 (best, 121.4 us) + A-PREFETCH DEPTH 4 as the single change:
// 8 A-LDS buffers (4 KB each, 32 KB total; still 2 blocks/CU). A-loads for
// tiles t+4,t+5 issue at top of pair P; their WRITE_A runs at top of pair
// P+1 -> a full pair body + barrier (~1500 cyc) covers the ~900-cyc HBM
// latency (R6 covered only ~1 COMPUTE, stalling each pair at WRITE_A).
// Hazard: buf (t+4)&7 last read at pair P-2, protected by the P-1 barrier.
// Everything else identical to R6 (staging map, swizzle, B path, epilogue).
// 512 thr / 8 waves (1M x 8N), wave tile 64x64, acc[4][4] (64 AGPR).
__global__ __launch_bounds__(512, 4)
void fused_kernel(const float* __restrict__ x,
                  const unsigned short* __restrict__ wb,
                  const float* __restrict__ bias,
                  const float* __restrict__ gamma,
                  const float* __restrict__ beta,
                  const float* __restrict__ scalep,
                  float* __restrict__ out) {
  __shared__ unsigned short As[8][64 * 32];    // 4 KB each, 32 KB total

  const int tid  = threadIdx.x;
  const int lane = tid & 63;
  const int wid  = tid >> 6;        // 0..7 = N eighth: cols wid*64..+63
  const int l15  = lane & 15;
  const int lg   = lane >> 4;       // 0..3

  const long bm  = (long)blockIdx.x * 64;

  f32x4 acc[4][4] = {};

  // ---- A staging: thread t loads x[bm + (t>>3)][ (t&7)*4 .. +3 ] per tile.
  //      8 threads cover one row's 128-B K-slice -> fully coalesced segments.
  //      LDS row = 64 B = 4 chunks of 16 B; chunk c at c ^ ((row>>1)&3).
  const int arow = tid >> 3;
  const int akq  = tid & 7;
  const float* asrc = x + (bm + arow) * KD + akq * 4;
  const int awb = arow * 64 + (((akq >> 1) ^ ((arow >> 1) & 3)) * 16)
                + ((akq & 1) * 8);

  // ---- A fragment read offsets: lane holds A[mi*16+l15][k = lg*8..+7] ----
  const int swa = (lg ^ ((l15 >> 1) & 3)) * 16;
  int ard[4];
  #pragma unroll
  for (int mi = 0; mi < 4; ++mi) ard[mi] = (mi * 16 + l15) * 64 + swa;

  // ---- B fragment base: frag ni of tile t at ((t*32 + wid*4+ni)*64+lane)*8 us
  const unsigned short* bbase = wb + ((size_t)(wid * 4) * 64 + lane) * 8;

#define LOADA(t) (*reinterpret_cast<const float4*>(asrc + (t) * 32))

#define LOADB(t, r0, r1, r2, r3) do { \
    const unsigned short* bp_ = bbase + (size_t)(t) * 16384; \
    r0 = *reinterpret_cast<const bf16x8*>(bp_ + 0 * 512); \
    r1 = *reinterpret_cast<const bf16x8*>(bp_ + 1 * 512); \
    r2 = *reinterpret_cast<const bf16x8*>(bp_ + 2 * 512); \
    r3 = *reinterpret_cast<const bf16x8*>(bp_ + 3 * 512); } while (0)

#define WRITE_A(q_, bufi) do { \
    union { unsigned short s[4]; unsigned long long v; } c_; \
    c_.s[0] = cvt1(q_.x); c_.s[1] = cvt1(q_.y); \
    c_.s[2] = cvt1(q_.z); c_.s[3] = cvt1(q_.w); \
    *reinterpret_cast<unsigned long long*>((char*)As[bufi] + awb) = c_.v; } while (0)

#define COMPUTE(bufi, B0, B1, B2, B3) do { \
    const char* ab_ = (const char*)As[bufi]; \
    bf16x8 a0_ = *reinterpret_cast<const bf16x8*>(ab_ + ard[0]); \
    bf16x8 a1_ = *reinterpret_cast<const bf16x8*>(ab_ + ard[1]); \
    bf16x8 a2_ = *reinterpret_cast<const bf16x8*>(ab_ + ard[2]); \
    bf16x8 a3_ = *reinterpret_cast<const bf16x8*>(ab_ + ard[3]); \
    acc[0][0] = __builtin_amdgcn_mfma_f32_16x16x32_bf16(a0_, B0, acc[0][0], 0, 0, 0); \
    acc[0][1] = __builtin_amdgcn_mfma_f32_16x16x32_bf16(a0_, B1, acc[0][1], 0, 0, 0); \
    acc[0][2] = __builtin_amdgcn_mfma_f32_16x16x32_bf16(a0_, B2, acc[0][2], 0, 0, 0); \
    acc[0][3] = __builtin_amdgcn_mfma_f32_16x16x32_bf16(a0_, B3, acc[0][3], 0, 0, 0); \
    acc[1][0] = __builtin_amdgcn_mfma_f32_16x16x32_bf16(a1_, B0, acc[1][0], 0, 0, 0); \
    acc[1][1] = __builtin_amdgcn_mfma_f32_16x16x32_bf16(a1_, B1, acc[1][1], 0, 0, 0); \
    acc[1][2] = __builtin_amdgcn_mfma_f32_16x16x32_bf16(a1_, B2, acc[1][2], 0, 0, 0); \
    acc[1][3] = __builtin_amdgcn_mfma_f32_16x16x32_bf16(a1_, B3, acc[1][3], 0, 0, 0); \
    acc[2][0] = __builtin_amdgcn_mfma_f32_16x16x32_bf16(a2_, B0, acc[2][0], 0, 0, 0); \
    acc[2][1] = __builtin_amdgcn_mfma_f32_16x16x32_bf16(a2_, B1, acc[2][1], 0, 0, 0); \
    acc[2][2] = __builtin_amdgcn_mfma_f32_16x16x32_bf16(a2_, B2, acc[2][2], 0, 0, 0); \
    acc[2][3] = __builtin_amdgcn_mfma_f32_16x16x32_bf16(a2_, B3, acc[2][3], 0, 0, 0); \
    acc[3][0] = __builtin_amdgcn_mfma_f32_16x16x32_bf16(a3_, B0, acc[3][0], 0, 0, 0); \
    acc[3][1] = __builtin_amdgcn_mfma_f32_16x16x32_bf16(a3_, B1, acc[3][1], 0, 0, 0); \
    acc[3][2] = __builtin_amdgcn_mfma_f32_16x16x32_bf16(a3_, B2, acc[3][2], 0, 0, 0); \
    acc[3][3] = __builtin_amdgcn_mfma_f32_16x16x32_bf16(a3_, B3, acc[3][3], 0, 0, 0); \
    } while (0)

  float4 qaE, qaO;
  bf16x8 bc0, bc1, bc2, bc3, bn0, bn1, bn2, bn3;

  // ---- prologue: stage A(0..3) into buf0..3; A(4),A(5) left in flight ----
  qaE = LOADA(0);
  qaO = LOADA(1);
  WRITE_A(qaE, 0);
  WRITE_A(qaO, 1);
  qaE = LOADA(2);
  qaO = LOADA(3);
  WRITE_A(qaE, 2);
  WRITE_A(qaO, 3);
  qaE = LOADA(4);
  qaO = LOADA(5);
  LOADB(0, bc0, bc1, bc2, bc3);
  __syncthreads();

  // pair loop: reads buf{t&7,(t+1)&7}; writes buf{(t+4)&7,(t+5)&7} (loads
  // issued one full pair earlier -> landed); issues A(t+6),A(t+7).
  for (int t = 0; t < NT; t += 2) {
    const int tp6 = (t + 6 < NT) ? t + 6 : NT - 1;   // clamped tail (harmless)
    const int tp7 = (t + 7 < NT) ? t + 7 : NT - 1;
    WRITE_A(qaE, (t + 4) & 7);          // in-flight since top of previous pair
    WRITE_A(qaO, (t + 5) & 7);
    qaE = LOADA(tp6);
    qaO = LOADA(tp7);
    LOADB(t + 1, bn0, bn1, bn2, bn3);
    SCHEDB();
    COMPUTE(t & 7, bc0, bc1, bc2, bc3);
    LOADB((t + 2 < NT) ? t + 2 : NT - 1, bc0, bc1, bc2, bc3);
    SCHEDB();
    COMPUTE((t + 1) & 7, bn0, bn1, bn2, bn3);
    __syncthreads();                    // publish this pair's two buffers
  }

  // ========== fused epilogue: bias + LN + scale + softmax (no-max) =========
  // |v| <= sqrt(ND) after LN (var=1) -> exp(v) <= 6.5e9, sum < 3.3e12: f32 ok.
  float* redS = (float*)As[0];  // [64][9] partial sums
  float* redQ = redS + 576;     // [64][9] partial sumsq / expsum
  float* rowA = redS + 1152;    // [64] mu
  float* rowB = redS + 1216;    // [64] rstd, later 1/expsum

  const int col0 = wid * 64 + l15;
  const float sc = scalep[0];
  float bs4[4], gs4[4], bb4[4];
  #pragma unroll
  for (int ni = 0; ni < 4; ++ni) {
    bs4[ni] = bias[col0 + ni * 16];
    gs4[ni] = gamma[col0 + ni * 16] * sc;
    bb4[ni] = beta[col0 + ni * 16] * sc;
  }

  // ---- pass 1: bias add + per-row sum / sumsq ----
  #pragma unroll
  for (int mi = 0; mi < 4; ++mi) {
    #pragma unroll
    for (int j = 0; j < 4; ++j) {
      float s = 0.f, q = 0.f;
      #pragma unroll
      for (int ni = 0; ni < 4; ++ni) {
        float v = acc[mi][ni][j] + bs4[ni];
        acc[mi][ni][j] = v;
        s += v;
        q = fmaf(v, v, q);
      }
      #pragma unroll
      for (int m = 1; m < 16; m <<= 1) {
        s += __shfl_xor(s, m, 64);
        q += __shfl_xor(q, m, 64);
      }
      if (l15 == 0) {
        int r = mi * 16 + lg * 4 + j;
        redS[r * 9 + wid] = s;
        redQ[r * 9 + wid] = q;
      }
    }
  }
  __syncthreads();
  if (tid < 64) {
    float s = 0.f, q = 0.f;
    #pragma unroll
    for (int k = 0; k < 8; ++k) { s += redS[tid * 9 + k]; q += redQ[tid * 9 + k]; }
    float mu = s * (1.f / ND);
    rowA[tid] = mu;
    rowB[tid] = rsqrtf(q * (1.f / ND) - mu * mu + EPSV);
  }
  __syncthreads();

  // ---- pass 2: normalize + scale + exp; per-row expsum ----
  #pragma unroll
  for (int mi = 0; mi < 4; ++mi) {
    #pragma unroll
    for (int j = 0; j < 4; ++j) {
      int r = mi * 16 + lg * 4 + j;
      float mu = rowA[r], rs = rowB[r];
      float ps = 0.f;
      #pragma unroll
      for (int ni = 0; ni < 4; ++ni) {
        float v = (acc[mi][ni][j] - mu) * rs;
        v = fmaf(v, gs4[ni], bb4[ni]);
        float e = __expf(v);
        acc[mi][ni][j] = e;
        ps += e;
      }
      #pragma unroll
      for (int m = 1; m < 16; m <<= 1) ps += __shfl_xor(ps, m, 64);
      if (l15 == 0) redQ[r * 9 + wid] = ps;
    }
  }
  __syncthreads();
  if (tid < 64) {
    float s = 0.f;
    #pragma unroll
    for (int k = 0; k < 8; ++k) s += redQ[tid * 9 + k];
    rowB[tid] = 1.f / s;
  }
  __syncthreads();

  // ---- pass 3: store out f32 (non-temporal) ----
  #pragma unroll
  for (int mi = 0; mi < 4; ++mi) {
    #pragma unroll
    for (int j = 0; j < 4; ++j) {
      int r = mi * 16 + lg * 4 + j;
      float rd = rowB[r];
      float* op = out + (bm + r) * ND + col0;
      #pragma unroll
      for (int ni = 0; ni < 4; ++ni)
        __builtin_nontemporal_store(acc[mi][ni][j] * rd, op + ni * 16);
    }
  }
#undef LOADA
#undef LOADB
#undef WRITE_A
#undef COMPUTE
}

// trivial last-resort fallback (ws too small; not expected in this harness)
__global__ void fused_fallback(const float* __restrict__ x,
                               const float* __restrict__ wf,
                               const float* __restrict__ bias,
                               const float* __restrict__ gamma,
                               const float* __restrict__ beta,
                               const float* __restrict__ scalep,
                               float* __restrict__ out) {
  long row = blockIdx.x;
  int t = threadIdx.x;
  float s = 0.f;
  const float* xr = x + row * KD;
  const float* wr_ = wf + (size_t)t * KD;
  for (int k = 0; k < KD; ++k) s += xr[k] * wr_[k];
  s += bias[t];
  __shared__ float buf[ND];
  buf[t] = s;
  __syncthreads();
  __shared__ float red[2];
  if (t == 0) {
    float sum = 0.f, sq = 0.f;
    for (int i = 0; i < ND; ++i) { sum += buf[i]; sq += buf[i] * buf[i]; }
    float mu = sum / ND;
    red[0] = mu;
    red[1] = rsqrtf(sq / ND - mu * mu + EPSV);
  }
  __syncthreads();
  float zv = (s - red[0]) * red[1] * gamma[t] * scalep[0] + beta[t] * scalep[0];
  buf[t] = zv;
  __syncthreads();
  __shared__ float red2[2];
  if (t == 0) {
    float mxv = -3.4e38f;
    for (int i = 0; i < ND; ++i) mxv = fmaxf(mxv, buf[i]);
    float den = 0.f;
    for (int i = 0; i < ND; ++i) den += __expf(buf[i] - mxv);
    red2[0] = mxv; red2[1] = 1.f / den;
  }
  __syncthreads();
  out[row * ND + t] = __expf(zv - red2[0]) * red2[1];
}

extern "C" void kernel_launch(void* const* d_in, const int* in_sizes, int n_in,
                              void* d_out, int out_size, void* d_ws, size_t ws_size,
                              hipStream_t stream) {
  const float* x     = (const float*)d_in[0];
  const float* w     = (const float*)d_in[1];
  const float* bias  = (const float*)d_in[2];
  const float* gamma = (const float*)d_in[3];
  const float* beta  = (const float*)d_in[4];
  const float* scale = (const float*)d_in[5];
  float* out = (float*)d_out;

  const int Mrows = in_sizes[0] / KD;                                  // 65536
  const size_t wb_bytes = (size_t)ND * KD * sizeof(unsigned short);    // 1 MB

  if (ws_size >= wb_bytes) {
    unsigned short* wbuf = (unsigned short*)d_ws;
    wconvert_kernel<<<(ND * KD / 8) / 256, 256, 0, stream>>>(w, wbuf);
    fused_kernel<<<Mrows / 64, 512, 0, stream>>>(x, wbuf, bias, gamma, beta,
                                                 scale, out);
  } else {
    fused_fallback<<<Mrows, ND, 0, stream>>>(x, w, bias, gamma, beta, scale, out);
  }
}